// Round 1
// baseline (167.156 us; speedup 1.0000x reference)
//
#include <hip/hip_runtime.h>

#define NQ 6
#define DIM 64
#define NL 8
#define NC 4

// ---------------------------------------------------------------------------
// Prep kernel: build the full 64x64 circuit unitary U (column per block, one
// amplitude per lane, partners exchanged via shfl_xor), plus M = Zsign @ fc_w^T.
// Layout in ws (floats): Wr[64*64] | Wi[64*64] | M[64*4]
// Bit convention: qubit q <-> bit (5-q) of the amplitude index (qubit 0 = MSB).
// ---------------------------------------------------------------------------
__global__ __launch_bounds__(64) void qnn_prep(
    const float* __restrict__ wts,   // [8*6*3] (phi, theta, omega)
    const float* __restrict__ fc_w,  // [4*6]
    float* __restrict__ ws)
{
    __shared__ float gc[48][4];      // per-gate: cp*ch, sp*ch, cm*sh, sm*sh
    const int n   = threadIdx.x;     // amplitude index 0..63
    const int col = blockIdx.x;      // basis column 0..63

    if (n < 48) {
        float phi = wts[n*3+0], th = wts[n*3+1], om = wts[n*3+2];
        float ch = cosf(0.5f*th), sh = sinf(0.5f*th);
        float p  = 0.5f*(phi+om), m  = 0.5f*(phi-om);
        gc[n][0] = cosf(p)*ch;
        gc[n][1] = sinf(p)*ch;
        gc[n][2] = cosf(m)*sh;
        gc[n][3] = sinf(m)*sh;
    }
    __syncthreads();

    float ar = (n == col) ? 1.0f : 0.0f;
    float ai = 0.0f;

    #pragma unroll
    for (int l = 0; l < NL; ++l) {
        // --- single-qubit Rot gates, q = 0..5 ---
        #pragma unroll
        for (int q = 0; q < NQ; ++q) {
            const int g     = l*NQ + q;
            const int shift = 5 - q;
            const int mask  = 1 << shift;
            const int b     = (n >> shift) & 1;
            const float cpch = gc[g][0];
            const float spch = gc[g][1];
            const float cmsh = gc[g][2];
            const float smsh = gc[g][3];
            const float pr = __shfl_xor(ar, mask, 64);
            const float pi = __shfl_xor(ai, mask, 64);
            // U = [[ (cpch,-spch), (-cmsh,-smsh) ],
            //      [ ( cmsh,-smsh), ( cpch, spch) ]]
            const float udr = cpch;
            const float udi = b ?  spch : -spch;
            const float uor = b ?  cmsh : -cmsh;
            const float uoi = -smsh;
            const float nr = udr*ar - udi*ai + uor*pr - uoi*pi;
            const float ni = udr*ai + udi*ar + uor*pi + uoi*pr;
            ar = nr; ai = ni;
        }
        // --- CNOT ring, control q -> target (q+r)%6, sequential in q ---
        const int r = (l % (NQ - 1)) + 1;
        #pragma unroll
        for (int q = 0; q < NQ; ++q) {
            const int t     = (q + r) % NQ;
            const int cmask = 1 << (5 - q);
            const int tmask = 1 << (5 - t);
            const float pr = __shfl_xor(ar, tmask, 64);
            const float pi = __shfl_xor(ai, tmask, 64);
            const bool ctrl = (n & cmask) != 0;
            ar = ctrl ? pr : ar;
            ai = ctrl ? pi : ai;
        }
    }

    // a[n] = <n|U|col>  => U[n][col]
    ws[n*DIM + col]            = ar;
    ws[DIM*DIM + n*DIM + col]  = ai;

    if (col == 0) {
        // M[n][c] = sum_q sign(n,q) * fc_w[c][q]
        float m0=0.f, m1=0.f, m2=0.f, m3=0.f;
        #pragma unroll
        for (int q = 0; q < NQ; ++q) {
            const float sgn = 1.0f - 2.0f*(float)((n >> (5-q)) & 1);
            m0 = fmaf(sgn, fc_w[0*NQ+q], m0);
            m1 = fmaf(sgn, fc_w[1*NQ+q], m1);
            m2 = fmaf(sgn, fc_w[2*NQ+q], m2);
            m3 = fmaf(sgn, fc_w[3*NQ+q], m3);
        }
        float* Mo = ws + 2*DIM*DIM;
        Mo[n*4+0]=m0; Mo[n*4+1]=m1; Mo[n*4+2]=m2; Mo[n*4+3]=m3;
    }
}

// ---------------------------------------------------------------------------
// Main kernel: one sample per lane. x[64] in VGPRs; W accessed with
// wave-uniform addresses (scalar loads); lane-local epilogue; float4 store.
// out[s][c] = (sum_i (re_i^2+im_i^2) * M[i][c]) / ||x||^2 + fc_b[c]
// ---------------------------------------------------------------------------
__global__ __launch_bounds__(256) void qnn_main(
    const float* __restrict__ x,
    const float* __restrict__ fc_b,
    const float* __restrict__ ws,
    float* __restrict__ out)
{
    const int s = blockIdx.x * 256 + threadIdx.x;
    const float* __restrict__ Wr = ws;
    const float* __restrict__ Wi = ws + DIM*DIM;
    const float* __restrict__ M  = ws + 2*DIM*DIM;

    float xr[DIM];
    const float4* __restrict__ xp = (const float4*)(x + (size_t)s * DIM);
    #pragma unroll
    for (int k = 0; k < DIM/4; ++k) {
        const float4 v = xp[k];
        xr[4*k+0]=v.x; xr[4*k+1]=v.y; xr[4*k+2]=v.z; xr[4*k+3]=v.w;
    }

    float ss = 0.f;
    #pragma unroll
    for (int j = 0; j < DIM; ++j) ss = fmaf(xr[j], xr[j], ss);

    float q0=0.f, q1=0.f, q2=0.f, q3=0.f;
    for (int i = 0; i < DIM; ++i) {
        float re = 0.f, im = 0.f;
        #pragma unroll
        for (int j = 0; j < DIM; ++j) re = fmaf(Wr[i*DIM+j], xr[j], re);
        #pragma unroll
        for (int j = 0; j < DIM; ++j) im = fmaf(Wi[i*DIM+j], xr[j], im);
        const float p = fmaf(re, re, im*im);
        q0 = fmaf(p, M[i*4+0], q0);
        q1 = fmaf(p, M[i*4+1], q1);
        q2 = fmaf(p, M[i*4+2], q2);
        q3 = fmaf(p, M[i*4+3], q3);
    }

    const float inv = 1.0f / ss;   // ss ~ chi^2_64, never near 0 for this input
    float4 o;
    o.x = fmaf(q0, inv, fc_b[0]);
    o.y = fmaf(q1, inv, fc_b[1]);
    o.z = fmaf(q2, inv, fc_b[2]);
    o.w = fmaf(q3, inv, fc_b[3]);
    ((float4*)out)[s] = o;
}

extern "C" void kernel_launch(void* const* d_in, const int* in_sizes, int n_in,
                              void* d_out, int out_size, void* d_ws, size_t ws_size,
                              hipStream_t stream) {
    const float* x    = (const float*)d_in[0];   // [262144, 64]
    const float* wts  = (const float*)d_in[1];   // [8, 6, 3]
    const float* fc_w = (const float*)d_in[2];   // [4, 6]
    const float* fc_b = (const float*)d_in[3];   // [4]
    float* out = (float*)d_out;                  // [262144, 4]
    float* ws  = (float*)d_ws;                   // needs (2*4096 + 256) floats = 33.8 KB

    const int batch = in_sizes[0] / DIM;         // 262144

    qnn_prep<<<DIM, DIM, 0, stream>>>(wts, fc_w, ws);
    qnn_main<<<batch / 256, 256, 0, stream>>>(x, fc_b, ws, out);
}

// Round 2
// 113.669 us; speedup vs baseline: 1.4705x; 1.4705x over previous
//
#include <hip/hip_runtime.h>

#define NQ 6
#define DIM 64
#define NL 8

#define KP  136   // Bs row pitch (bf16 elems); 272 B rows: 16B aligned, bank-stride 68 words -> 2-way (free)
#define APT 72    // As row pitch (bf16 elems); 144 B rows: 16B aligned
#define ROWS 128  // samples per block
#define PSP 68    // Ps row pitch (floats), reuses Bs region: 128*68*4 = 34816 B = sizeof(Bs)

typedef __attribute__((ext_vector_type(8))) short short8v;   // 8 bf16 = 4 VGPRs
typedef __attribute__((ext_vector_type(4))) float floatx4;

__device__ inline unsigned short f2bf_rne(float f) {
    unsigned u = __float_as_uint(f);
    u += 0x7FFF + ((u >> 16) & 1);           // round-to-nearest-even
    return (unsigned short)(u >> 16);
}

// ---------------------------------------------------------------------------
// Prep: build circuit unitary U (verified in round 1), emit to ws:
//   Bs[128][KP] bf16 : rows n<64 = Wr[n][*], n>=64 = Wi[n-64][*];
//                      cols k<64 = bf16_hi(W[n][k]), 64<=k<128 = bf16_lo(W[n][k])
//   M[64][4] fp32 at byte offset 128*KP*2
// ---------------------------------------------------------------------------
__global__ __launch_bounds__(64) void qnn_prep(
    const float* __restrict__ wts,   // [8*6*3] (phi, theta, omega)
    const float* __restrict__ fc_w,  // [4*6]
    void* __restrict__ ws)
{
    __shared__ float gc[48][4];
    const int n   = threadIdx.x;     // amplitude row 0..63
    const int col = blockIdx.x;      // basis column 0..63

    if (n < 48) {
        float phi = wts[n*3+0], th = wts[n*3+1], om = wts[n*3+2];
        float ch = cosf(0.5f*th), sh = sinf(0.5f*th);
        float p  = 0.5f*(phi+om), m  = 0.5f*(phi-om);
        gc[n][0] = cosf(p)*ch;
        gc[n][1] = sinf(p)*ch;
        gc[n][2] = cosf(m)*sh;
        gc[n][3] = sinf(m)*sh;
    }
    __syncthreads();

    float ar = (n == col) ? 1.0f : 0.0f;
    float ai = 0.0f;

    #pragma unroll
    for (int l = 0; l < NL; ++l) {
        #pragma unroll
        for (int q = 0; q < NQ; ++q) {
            const int g     = l*NQ + q;
            const int shift = 5 - q;
            const int mask  = 1 << shift;
            const int b     = (n >> shift) & 1;
            const float cpch = gc[g][0];
            const float spch = gc[g][1];
            const float cmsh = gc[g][2];
            const float smsh = gc[g][3];
            const float pr = __shfl_xor(ar, mask, 64);
            const float pi = __shfl_xor(ai, mask, 64);
            const float udr = cpch;
            const float udi = b ?  spch : -spch;
            const float uor = b ?  cmsh : -cmsh;
            const float uoi = -smsh;
            const float nr = udr*ar - udi*ai + uor*pr - uoi*pi;
            const float ni = udr*ai + udi*ar + uor*pi + uoi*pr;
            ar = nr; ai = ni;
        }
        const int r = (l % (NQ - 1)) + 1;
        #pragma unroll
        for (int q = 0; q < NQ; ++q) {
            const int t     = (q + r) % NQ;
            const int cmask = 1 << (5 - q);
            const int tmask = 1 << (5 - t);
            const float pr = __shfl_xor(ar, tmask, 64);
            const float pi = __shfl_xor(ai, tmask, 64);
            const bool ctrl = (n & cmask) != 0;
            ar = ctrl ? pr : ar;
            ai = ctrl ? pi : ai;
        }
    }

    // (ar, ai) = U[n][col]
    unsigned short* Bs = (unsigned short*)ws;
    unsigned short hr = f2bf_rne(ar);
    float hrf = __uint_as_float((unsigned)hr << 16);
    unsigned short lr = f2bf_rne(ar - hrf);
    unsigned short hi = f2bf_rne(ai);
    float hif = __uint_as_float((unsigned)hi << 16);
    unsigned short li = f2bf_rne(ai - hif);
    Bs[n*KP + col]           = hr;
    Bs[n*KP + 64 + col]      = lr;
    Bs[(64+n)*KP + col]      = hi;
    Bs[(64+n)*KP + 64 + col] = li;

    if (col == 0) {
        float m0=0.f, m1=0.f, m2=0.f, m3=0.f;
        #pragma unroll
        for (int q = 0; q < NQ; ++q) {
            const float sgn = 1.0f - 2.0f*(float)((n >> (5-q)) & 1);
            m0 = fmaf(sgn, fc_w[0*NQ+q], m0);
            m1 = fmaf(sgn, fc_w[1*NQ+q], m1);
            m2 = fmaf(sgn, fc_w[2*NQ+q], m2);
            m3 = fmaf(sgn, fc_w[3*NQ+q], m3);
        }
        float* Mo = (float*)((char*)ws + 128*KP*2);
        Mo[n*4+0]=m0; Mo[n*4+1]=m1; Mo[n*4+2]=m2; Mo[n*4+3]=m3;
    }
}

// ---------------------------------------------------------------------------
// Main: 128 samples/block, 4 waves. Each wave: 2 M-tiles x 8 N-tiles (re|im)
// x 4 K-steps of mfma_f32_16x16x32_bf16. A = [xh | xh] (K idx k<64 and
// 64<=k<128 both read xh), B = [Wh ; Wl]  =>  re/im = xh . W (exact in W).
// Epilogue: p = re^2+im^2 -> LDS (reuse Bs), out = (p@M)/(sum p) + b.
// ---------------------------------------------------------------------------
__global__ __launch_bounds__(256) void qnn_main(
    const float* __restrict__ x,
    const float* __restrict__ fc_b,
    const void* __restrict__ wsv,
    float* __restrict__ out)
{
    __shared__ __align__(16) unsigned short Bs[128*KP];   // 34816 B
    __shared__ __align__(16) unsigned short As[ROWS*APT]; // 18432 B
    __shared__ float Ml[DIM*4];                           // 1024 B

    const int tid = threadIdx.x;
    const int s0  = blockIdx.x * ROWS;

    // --- stage B (bf16, already padded to pitch KP in ws) ---
    {
        const floatx4* bg = (const floatx4*)wsv;
        floatx4* bl = (floatx4*)Bs;
        #pragma unroll
        for (int i = 0; i < (128*KP*2/16 + 255)/256; ++i) {
            int idx = tid + i*256;
            if (idx < 128*KP*2/16) bl[idx] = bg[idx];
        }
        const float* Mg = (const float*)((const char*)wsv + 128*KP*2);
        Ml[tid] = Mg[tid];   // 256 floats
    }

    // --- stage A: bf16_hi(x), row-major, pitch APT ---
    {
        const float4* xg = (const float4*)(x + (size_t)s0 * DIM);
        unsigned* A32 = (unsigned*)As;
        #pragma unroll
        for (int i = 0; i < 8; ++i) {
            int f = tid + i*256;          // flat float4 index in [0, 2048)
            int s = f >> 4, q = f & 15;
            float4 v = xg[(s << 4) + q];
            unsigned short h0 = f2bf_rne(v.x), h1 = f2bf_rne(v.y);
            unsigned short h2 = f2bf_rne(v.z), h3 = f2bf_rne(v.w);
            int w0 = s*(APT/2) + q*2;
            A32[w0]   = ((unsigned)h1 << 16) | h0;
            A32[w0+1] = ((unsigned)h3 << 16) | h2;
        }
    }
    __syncthreads();

    const int lane = tid & 63;
    const int w    = tid >> 6;
    const int l15  = lane & 15;
    const int quad = lane >> 4;

    floatx4 acc[2][8];
    #pragma unroll
    for (int mt = 0; mt < 2; ++mt)
        #pragma unroll
        for (int nt = 0; nt < 8; ++nt)
            acc[mt][nt] = (floatx4){0.f, 0.f, 0.f, 0.f};

    #pragma unroll
    for (int kk = 0; kk < 4; ++kk) {
        const int ak = ((kk & 1) << 5) + quad*8;     // A k-offset (xh reread for k>=64)
        const int bk = (kk << 5) + quad*8;           // B k-offset (Wh then Wl)
        short8v a0 = *(const short8v*)&As[(w*32 +      l15)*APT + ak];
        short8v a1 = *(const short8v*)&As[(w*32 + 16 + l15)*APT + ak];
        #pragma unroll
        for (int nt = 0; nt < 8; ++nt) {
            short8v b = *(const short8v*)&Bs[(nt*16 + l15)*KP + bk];
            acc[0][nt] = __builtin_amdgcn_mfma_f32_16x16x32_bf16(a0, b, acc[0][nt], 0, 0, 0);
            acc[1][nt] = __builtin_amdgcn_mfma_f32_16x16x32_bf16(a1, b, acc[1][nt], 0, 0, 0);
        }
    }

    __syncthreads();   // all waves done reading Bs/As
    // --- p = re^2 + im^2 into Ps (reuses Bs region) ---
    float* Ps = (float*)Bs;
    #pragma unroll
    for (int mt = 0; mt < 2; ++mt)
        #pragma unroll
        for (int nt = 0; nt < 4; ++nt)
            #pragma unroll
            for (int r = 0; r < 4; ++r) {
                float re = acc[mt][nt][r];
                float im = acc[mt][nt + 4][r];
                int srow = w*32 + mt*16 + quad*4 + r;        // C: row = quad*4+reg
                Ps[srow*PSP + nt*16 + l15] = fmaf(re, re, im*im);  // col = lane&15
            }
    __syncthreads();

    // --- epilogue: out[s][c] = (sum_col p*M[col][c]) / (sum_col p) + b[c] ---
    {
        const int sA = tid >> 2, c = tid & 3;
        const float bc = fc_b[c];
        float sum0 = 0.f, ss0 = 0.f, sum1 = 0.f, ss1 = 0.f;
        #pragma unroll
        for (int col = 0; col < DIM; ++col) {
            float m  = Ml[col*4 + c];
            float p0 = Ps[sA*PSP + col];
            float p1 = Ps[(sA + 64)*PSP + col];
            ss0 += p0; sum0 = fmaf(p0, m, sum0);
            ss1 += p1; sum1 = fmaf(p1, m, sum1);
        }
        out[(size_t)(s0 + sA)*4 + c]      = sum0/ss0 + bc;
        out[(size_t)(s0 + sA + 64)*4 + c] = sum1/ss1 + bc;
    }
}

extern "C" void kernel_launch(void* const* d_in, const int* in_sizes, int n_in,
                              void* d_out, int out_size, void* d_ws, size_t ws_size,
                              hipStream_t stream) {
    const float* x    = (const float*)d_in[0];   // [262144, 64]
    const float* wts  = (const float*)d_in[1];   // [8, 6, 3]
    const float* fc_w = (const float*)d_in[2];   // [4, 6]
    const float* fc_b = (const float*)d_in[3];   // [4]
    float* out = (float*)d_out;                  // [262144, 4]

    const int batch = in_sizes[0] / DIM;         // 262144

    qnn_prep<<<DIM, DIM, 0, stream>>>(wts, fc_w, d_ws);
    qnn_main<<<batch / ROWS, 256, 0, stream>>>(x, fc_b, d_ws, out);
}